// Round 2
// baseline (189.527 us; speedup 1.0000x reference)
//
#include <hip/hip_runtime.h>

// EdgeSampler: one-hop neighbor sampling with replacement over CSR adjacency.
// Inputs (setup_inputs order):
//   d_in[0] source_node_ids  int32   [256*512]        = 131072
//   d_in[1] row_ptr          int32   [1000001]
//   d_in[2] col_indices      int32   [~32M]
//   d_in[3] rand_u           float32 [256*512*16]     = 2097152
// Output (tuple concatenated flat, int32):
//   d_out[0        .. 2097151]  src
//   d_out[2097152  .. 4194303]  tgt
//   d_out[4194304  .. 6291455]  valid
//
// R6 EXPERIMENT: one sample per thread (2M threads) instead of 4/thread.
// Theory: kernel is read-miss-slot bound (all pipes idle at 184us; streaming
// roofline is ~10us). Previous layout issued 4 back-to-back gather instrs per
// thread into the SAME ~128B neighbor span -> each seed's col granules
// requested ~4x (intra-instruction dedup only). One-sample-per-thread makes
// every sample exactly one gather lane; per-span granules requested once per
// instruction across 4x fewer instructions (~1.1M -> ~0.6M read granule reqs).
// Predict: ~100-120us if MSHR-duplication theory holds; neutral if the L1
// merges in-flight duplicate granules (then next lever = latency depth).

#define NUM_SAMPLES (256 * 512 * 16)           // 2,097,152 = one thread each

__global__ __launch_bounds__(256) void EdgeSampler_62947040690666_kernel(
    const int*   __restrict__ src_ids,      // [B*R]
    const int*   __restrict__ row_ptr,      // [N+1]
    const int*   __restrict__ col_idx,      // [E]
    const float* __restrict__ rand_u,       // [B*R*S]
    int* __restrict__ out_src,
    int* __restrict__ out_tgt,
    int* __restrict__ out_valid)
{
    int tid = blockIdx.x * blockDim.x + threadIdx.x;   // grid sized exactly

    // 16 consecutive threads share one seed -> src/row_ptr loads merge into
    // very few granules per wave (4 distinct seeds per 64-lane wave).
    int seed_idx = tid >> 4;
    int seed  = src_ids[seed_idx];
    int start = row_ptr[seed];
    int deg   = row_ptr[seed + 1] - start;

    // Streaming read — scalar, fully coalesced (4B/lane), no reuse.
    float u = __builtin_nontemporal_load(&rand_u[tid]);

    int hi = deg - 1; if (hi < 0) hi = 0;
    int i0 = (int)(u * (float)deg); if (i0 > hi) i0 = hi;

    bool valid = (deg > 0);
    int base = valid ? start : 0;   // deg==0: reference gathers col_indices[0]

    // ONE gather lane per sample — no duplicate span requests across instrs.
    int t0 = col_idx[base + i0];

    // Non-temporal scalar stores: adjacent lanes adjacent addresses (coalesced).
    __builtin_nontemporal_store(seed,           &out_src[tid]);
    __builtin_nontemporal_store(t0,             &out_tgt[tid]);
    __builtin_nontemporal_store(valid ? 1 : 0,  &out_valid[tid]);
}

extern "C" void kernel_launch(void* const* d_in, const int* in_sizes, int n_in,
                              void* d_out, int out_size, void* d_ws, size_t ws_size,
                              hipStream_t stream) {
    const int*   src_ids = (const int*)d_in[0];
    const int*   row_ptr = (const int*)d_in[1];
    const int*   col_idx = (const int*)d_in[2];
    const float* rand_u  = (const float*)d_in[3];

    int* out = (int*)d_out;
    int* out_src   = out;
    int* out_tgt   = out + NUM_SAMPLES;
    int* out_valid = out + 2 * NUM_SAMPLES;

    const int block = 256;
    const int grid  = NUM_SAMPLES / block;   // 8192 blocks, exact
    EdgeSampler_62947040690666_kernel<<<grid, block, 0, stream>>>(
        src_ids, row_ptr, col_idx, rand_u, out_src, out_tgt, out_valid);
}

// Round 3
// 189.000 us; speedup vs baseline: 1.0028x; 1.0028x over previous
//
#include <hip/hip_runtime.h>

// EdgeSampler: one-hop neighbor sampling with replacement over CSR adjacency.
// Inputs (setup_inputs order):
//   d_in[0] source_node_ids  int32   [256*512]        = 131072
//   d_in[1] row_ptr          int32   [1000001]
//   d_in[2] col_indices      int32   [~32M]
//   d_in[3] rand_u           float32 [256*512*16]     = 2097152
// Output (tuple concatenated flat, int32):
//   d_out[0        .. 2097151]  src
//   d_out[2097152  .. 4194303]  tgt
//   d_out[4194304  .. 6291455]  valid
//
// R7 EXPERIMENT: two-kernel launch — (1) sequential L3-warm of col_indices +
// row_ptr, (2) the proven R4 sampler.
// Theory: R4 (4 gathers/thread) == R6 (1/thread) == ~185us, yet the sampler
// never shows in rocprof top-5 (so it runs <77us in the profile pass), and the
// streaming roofline is ~10us. The timed iteration starts right after 500MB
// poison fills: L3 is full of dirty lines and holds none of our inputs, so
// every random gather is an HBM miss queued behind writeback drain. Converting
// those random HBM reads into ONE sequential 132MB sweep (full BW, absorbs the
// L3 eviction cost) and serving the sampler's gathers from L3 attacks the
// actual regime. Predict: total 80-110us (prefetch 25-40 + sampler 40-70).
// Neutral result would falsify HBM-side latency as the bottleneck.

#define NUM_SAMPLES (256 * 512 * 16)           // 2,097,152
#define NUM_THREADS (NUM_SAMPLES / 4)          // 524,288 (sampler, 4/thread)

typedef int   vint4   __attribute__((ext_vector_type(4)));
typedef float vfloat4 __attribute__((ext_vector_type(4)));

// --- Kernel 1: sequential warm of col_indices + row_ptr into L3 -------------
// Infinity Cache is memory-side: any HBM read allocates. Grid-stride dwordx4
// sweep = full streaming BW. No stores; loads kept alive via asm (rule #17).
__global__ __launch_bounds__(256) void EdgeSampler_62947040690666_prefetch(
    const vint4* __restrict__ col4, long n_col4,
    const vint4* __restrict__ row4, long n_row4)
{
    long tid    = (long)blockIdx.x * blockDim.x + threadIdx.x;
    long stride = (long)gridDim.x * blockDim.x;
    int acc = 0;
    for (long i = tid; i < n_col4; i += stride) {
        vint4 v = col4[i];
        acc += v.x + v.y + v.z + v.w;
    }
    for (long i = tid; i < n_row4; i += stride) {
        vint4 v = row4[i];
        acc += v.x + v.y + v.z + v.w;
    }
    asm volatile("" :: "v"(acc));   // DCE guard — keeps the sweep loads live
}

// --- Kernel 2: the R4 sampler (best measured: 184.1us cold) -----------------
__global__ __launch_bounds__(256) void EdgeSampler_62947040690666_kernel(
    const int* __restrict__ src_ids,      // [B*R]
    const int* __restrict__ row_ptr,      // [N+1]
    const int* __restrict__ col_idx,      // [E]
    const vfloat4* __restrict__ rand4,    // [B*R*S/4]
    vint4* __restrict__ out_src,
    vint4* __restrict__ out_tgt,
    vint4* __restrict__ out_valid)
{
    int tid = blockIdx.x * blockDim.x + threadIdx.x;   // grid sized exactly

    // 4 consecutive threads share one seed -> L1-broadcast row_ptr loads.
    int seed_idx = tid >> 2;
    int seed  = src_ids[seed_idx];
    int start = row_ptr[seed];
    int deg   = row_ptr[seed + 1] - start;

    // Streaming read — bypass cache retention (no reuse of rand_u).
    vfloat4 u = __builtin_nontemporal_load(&rand4[tid]);

    float degf = (float)deg;
    int hi = deg - 1; if (hi < 0) hi = 0;

    int i0 = (int)(u.x * degf); if (i0 > hi) i0 = hi;
    int i1 = (int)(u.y * degf); if (i1 > hi) i1 = hi;
    int i2 = (int)(u.z * degf); if (i2 > hi) i2 = hi;
    int i3 = (int)(u.w * degf); if (i3 > hi) i3 = hi;

    bool valid = (deg > 0);
    int base = valid ? start : 0;   // deg==0: reference gathers col_indices[0]

    // 4 independent gathers — L3-hot after the prefetch kernel.
    int t0 = col_idx[base + i0];
    int t1 = col_idx[base + i1];
    int t2 = col_idx[base + i2];
    int t3 = col_idx[base + i3];

    int v = valid ? 1 : 0;
    vint4 vsrc = (vint4){seed, seed, seed, seed};
    vint4 vtgt = (vint4){t0, t1, t2, t3};
    vint4 vval = (vint4){v, v, v, v};

    // Non-temporal: outputs are write-once; keep L3 for col_idx lines.
    __builtin_nontemporal_store(vsrc, &out_src[tid]);
    __builtin_nontemporal_store(vtgt, &out_tgt[tid]);
    __builtin_nontemporal_store(vval, &out_valid[tid]);
}

extern "C" void kernel_launch(void* const* d_in, const int* in_sizes, int n_in,
                              void* d_out, int out_size, void* d_ws, size_t ws_size,
                              hipStream_t stream) {
    const int*     src_ids = (const int*)d_in[0];
    const int*     row_ptr = (const int*)d_in[1];
    const int*     col_idx = (const int*)d_in[2];
    const vfloat4* rand4   = (const vfloat4*)d_in[3];

    int* out = (int*)d_out;
    vint4* out_src   = (vint4*)(out);
    vint4* out_tgt   = (vint4*)(out + NUM_SAMPLES);
    vint4* out_valid = (vint4*)(out + 2 * NUM_SAMPLES);

    // Runtime-sized sweep: in_sizes are bytes. Round down to whole int4s —
    // missing a <=12B tail is harmless for a cache warm.
    long n_col4 = (long)in_sizes[2] / 16;
    long n_row4 = (long)in_sizes[1] / 16;

    const int block = 256;
    EdgeSampler_62947040690666_prefetch<<<2048, block, 0, stream>>>(
        (const vint4*)col_idx, n_col4, (const vint4*)row_ptr, n_row4);

    const int grid = NUM_THREADS / block;   // 2048 blocks, exact
    EdgeSampler_62947040690666_kernel<<<grid, block, 0, stream>>>(
        src_ids, row_ptr, col_idx, rand4, out_src, out_tgt, out_valid);
}

// Round 4
// 188.774 us; speedup vs baseline: 1.0040x; 1.0012x over previous
//
#include <hip/hip_runtime.h>

// EdgeSampler: one-hop neighbor sampling with replacement over CSR adjacency.
// Inputs (setup_inputs order):
//   d_in[0] source_node_ids  int32   [256*512]        = 131072
//   d_in[1] row_ptr          int32   [1000001]
//   d_in[2] col_indices      int32   [~32M]
//   d_in[3] rand_u           float32 [256*512*16]     = 2097152
// Output (tuple concatenated flat, int32):
//   d_out[0        .. 2097151]  src
//   d_out[2097152  .. 4194303]  tgt
//   d_out[4194304  .. 6291455]  valid
//
// R8: FUSED sweep+sample, one dispatch.
// Model from R4/R6/R7: dur_us = ~107us fixed harness re-poison (500MB fill @
// 77us is INSIDE the timed iteration; ~50 fills visible in profile) + our
// kernel time (R4 cold sampler = ~76us; never in top-5 => <77us). R7 showed
// L3-warming the graph pays for the sampler (~-20us) but the serialized
// second launch ate the gain. Fix: fuse. All 2048 blocks are co-resident
// (8 blk/CU, max occupancy), so the per-block sequential sweep of
// row_ptr+col_indices (132MB total) runs at full streaming BW in parallel,
// absorbs the dirty-poison L3 eviction once, then each block falls through
// __syncthreads() into R4 sampling with gathers L3-resident. No relaunch,
// no grid drain, sweep tails overlap early finishers' sampling.
// Predict: fused kernel 45-60us -> dur_us 150-165. Neutral again would
// falsify the floor model (next: 2x-work A/B calibration of dur_us).

#define NUM_SAMPLES (256 * 512 * 16)           // 2,097,152
#define NUM_THREADS (NUM_SAMPLES / 4)          // 524,288 (4 samples/thread)

typedef int   vint4   __attribute__((ext_vector_type(4)));
typedef float vfloat4 __attribute__((ext_vector_type(4)));

__global__ __launch_bounds__(256) void EdgeSampler_62947040690666_kernel(
    const int* __restrict__ src_ids,      // [B*R]
    const int* __restrict__ row_ptr,      // [N+1]
    const int* __restrict__ col_idx,      // [E]
    const vfloat4* __restrict__ rand4,    // [B*R*S/4]
    vint4* __restrict__ out_src,
    vint4* __restrict__ out_tgt,
    vint4* __restrict__ out_valid,
    int n_row4, int n_col4)               // int4 counts for the sweep
{
    int tid = blockIdx.x * blockDim.x + threadIdx.x;   // grid sized exactly

    // ---- Phase 1: cooperative sequential warm of row_ptr then col_indices.
    // Regular (allocating) loads on purpose — we WANT L3 residency.
    // Coalesced grid-stride: stride = 524288 threads, ~16 iters over col.
    const vint4* row4 = (const vint4*)row_ptr;
    const vint4* col4 = (const vint4*)col_idx;
    int acc = 0;
    for (int i = tid; i < n_row4; i += NUM_THREADS) {
        vint4 v = row4[i];
        acc += v.x + v.y + v.z + v.w;
    }
    for (int i = tid; i < n_col4; i += NUM_THREADS) {
        vint4 v = col4[i];
        acc += v.x + v.y + v.z + v.w;
    }
    asm volatile("" :: "v"(acc));   // DCE guard (rule #17) — keep sweep loads
    // Barrier drains this block's sweep loads (implies vmcnt(0)) and orders
    // the gathers after the warm; other blocks' sweeps run concurrently.
    __syncthreads();

    // ---- Phase 2: R4 sampling (proven correct, 184.1us cold standalone).
    // 4 consecutive threads share one seed -> L1-broadcast row_ptr loads.
    int seed_idx = tid >> 2;
    int seed  = src_ids[seed_idx];
    int start = row_ptr[seed];
    int deg   = row_ptr[seed + 1] - start;

    // Streaming read — bypass cache retention (no reuse of rand_u).
    vfloat4 u = __builtin_nontemporal_load(&rand4[tid]);

    float degf = (float)deg;
    int hi = deg - 1; if (hi < 0) hi = 0;

    int i0 = (int)(u.x * degf); if (i0 > hi) i0 = hi;
    int i1 = (int)(u.y * degf); if (i1 > hi) i1 = hi;
    int i2 = (int)(u.z * degf); if (i2 > hi) i2 = hi;
    int i3 = (int)(u.w * degf); if (i3 > hi) i3 = hi;

    bool valid = (deg > 0);
    int base = valid ? start : 0;   // deg==0: reference gathers col_indices[0]

    // 4 independent gathers — L3-resident after the fused sweep.
    int t0 = col_idx[base + i0];
    int t1 = col_idx[base + i1];
    int t2 = col_idx[base + i2];
    int t3 = col_idx[base + i3];

    int v = valid ? 1 : 0;
    vint4 vsrc = (vint4){seed, seed, seed, seed};
    vint4 vtgt = (vint4){t0, t1, t2, t3};
    vint4 vval = (vint4){v, v, v, v};

    // Non-temporal: outputs are write-once; don't evict col_idx from L3.
    __builtin_nontemporal_store(vsrc, &out_src[tid]);
    __builtin_nontemporal_store(vtgt, &out_tgt[tid]);
    __builtin_nontemporal_store(vval, &out_valid[tid]);
}

extern "C" void kernel_launch(void* const* d_in, const int* in_sizes, int n_in,
                              void* d_out, int out_size, void* d_ws, size_t ws_size,
                              hipStream_t stream) {
    const int*     src_ids = (const int*)d_in[0];
    const int*     row_ptr = (const int*)d_in[1];
    const int*     col_idx = (const int*)d_in[2];
    const vfloat4* rand4   = (const vfloat4*)d_in[3];

    int* out = (int*)d_out;
    vint4* out_src   = (vint4*)(out);
    vint4* out_tgt   = (vint4*)(out + NUM_SAMPLES);
    vint4* out_valid = (vint4*)(out + 2 * NUM_SAMPLES);

    // Sweep bounds in whole int4s (missing a <=12B tail is harmless).
    int n_row4 = in_sizes[1] / 16;
    int n_col4 = in_sizes[2] / 16;

    const int block = 256;
    const int grid  = NUM_THREADS / block;   // 2048 blocks, all co-resident
    EdgeSampler_62947040690666_kernel<<<grid, block, 0, stream>>>(
        src_ids, row_ptr, col_idx, rand4, out_src, out_tgt, out_valid,
        n_row4, n_col4);
}

// Round 5
// 185.061 us; speedup vs baseline: 1.0241x; 1.0201x over previous
//
#include <hip/hip_runtime.h>

// EdgeSampler: one-hop neighbor sampling with replacement over CSR adjacency.
// Inputs (setup_inputs order):
//   d_in[0] source_node_ids  int32   [256*512]        = 131072
//   d_in[1] row_ptr          int32   [1000001]
//   d_in[2] col_indices      int32   [~32M]
//   d_in[3] rand_u           float32 [256*512*16]     = 2097152
// Output (tuple concatenated flat, int32):
//   d_out[0        .. 2097151]  src
//   d_out[2097152  .. 4194303]  tgt
//   d_out[4194304  .. 6291455]  valid
//
// R9 CALIBRATION PROBE (pre-committed in R8): R4's kernel with the entire
// sampling phase executed TWICE. The second pass recomputes identical values
// (idempotent stores => still correct); an asm memory clobber between passes
// forces every load (src, row_ptr, col_idx, rand_u) to re-issue, so VMEM
// work genuinely ~doubles (pass 2 cache-warm).
// Why: four structurally different kernels (R4/R6/R7/R8, including one with
// an extra 132MB sweep) all measured 184-190us, and our dispatch never
// appears in rocprof top-5 (< 74us in every variant). Either dur_us is
// additive and all four coincidentally cost ~76us, or the measurement has a
// fixed floor with our kernel off the critical path. This probe decides:
//   dur_us >= ~220  -> additive; kernel ~40-80us; resume optimization
//                      (queued: seed-sorted gather locality).
//   dur_us 184-195  -> harness floor; kernel improvements cannot show;
//                      declare measurement-floor next round.

#define NUM_SAMPLES (256 * 512 * 16)           // 2,097,152
#define NUM_THREADS (NUM_SAMPLES / 4)          // 524,288 (4 samples/thread)

typedef int   vint4   __attribute__((ext_vector_type(4)));
typedef float vfloat4 __attribute__((ext_vector_type(4)));

__global__ __launch_bounds__(256) void EdgeSampler_62947040690666_kernel(
    const int* __restrict__ src_ids,      // [B*R]
    const int* __restrict__ row_ptr,      // [N+1]
    const int* __restrict__ col_idx,      // [E]
    const vfloat4* __restrict__ rand4,    // [B*R*S/4]
    vint4* __restrict__ out_src,
    vint4* __restrict__ out_tgt,
    vint4* __restrict__ out_valid)
{
    int tid = blockIdx.x * blockDim.x + threadIdx.x;   // grid sized exactly

    #pragma unroll 1
    for (int pass = 0; pass < 2; ++pass) {
        // 4 consecutive threads share one seed -> L1-broadcast row_ptr loads.
        int seed_idx = tid >> 2;
        int seed  = src_ids[seed_idx];
        int start = row_ptr[seed];
        int deg   = row_ptr[seed + 1] - start;

        // Streaming read — bypass cache retention (no reuse of rand_u).
        vfloat4 u = __builtin_nontemporal_load(&rand4[tid]);

        float degf = (float)deg;
        int hi = deg - 1; if (hi < 0) hi = 0;

        int i0 = (int)(u.x * degf); if (i0 > hi) i0 = hi;
        int i1 = (int)(u.y * degf); if (i1 > hi) i1 = hi;
        int i2 = (int)(u.z * degf); if (i2 > hi) i2 = hi;
        int i3 = (int)(u.w * degf); if (i3 > hi) i3 = hi;

        bool valid = (deg > 0);
        int base = valid ? start : 0;  // deg==0: reference gathers col_indices[0]

        // 4 independent gathers — MLP within one thread.
        int t0 = col_idx[base + i0];
        int t1 = col_idx[base + i1];
        int t2 = col_idx[base + i2];
        int t3 = col_idx[base + i3];

        int v = valid ? 1 : 0;
        vint4 vsrc = (vint4){seed, seed, seed, seed};
        vint4 vtgt = (vint4){t0, t1, t2, t3};
        vint4 vval = (vint4){v, v, v, v};

        // Non-temporal: outputs are write-once (twice here, idempotent).
        __builtin_nontemporal_store(vsrc, &out_src[tid]);
        __builtin_nontemporal_store(vtgt, &out_tgt[tid]);
        __builtin_nontemporal_store(vval, &out_valid[tid]);

        // Force pass 2 to re-issue every load (defeat CSE across passes).
        asm volatile("" ::: "memory");
    }
}

extern "C" void kernel_launch(void* const* d_in, const int* in_sizes, int n_in,
                              void* d_out, int out_size, void* d_ws, size_t ws_size,
                              hipStream_t stream) {
    const int*     src_ids = (const int*)d_in[0];
    const int*     row_ptr = (const int*)d_in[1];
    const int*     col_idx = (const int*)d_in[2];
    const vfloat4* rand4   = (const vfloat4*)d_in[3];

    int* out = (int*)d_out;
    vint4* out_src   = (vint4*)(out);
    vint4* out_tgt   = (vint4*)(out + NUM_SAMPLES);
    vint4* out_valid = (vint4*)(out + 2 * NUM_SAMPLES);

    const int block = 256;
    const int grid  = NUM_THREADS / block;   // 2048 blocks, exact
    EdgeSampler_62947040690666_kernel<<<grid, block, 0, stream>>>(
        src_ids, row_ptr, col_idx, rand4, out_src, out_tgt, out_valid);
}